// Round 3
// baseline (1892.402 us; speedup 1.0000x reference)
//
#include <hip/hip_runtime.h>
#include <math.h>

// B=4, N=256, H=256, HEADS=4, DH=64, FF=1024, V=256, L=128
// rows BN = 1024

__device__ __forceinline__ float gelu_f(float x) {
    return 0.5f * x * (1.0f + erff(x * 0.7071067811865476f));
}

// ---------------- stage 0: lat, time_e, size_logits ----------------
__global__ __launch_bounds__(256) void k_head0(
    const float* __restrict__ z, const float* __restrict__ lp1w, const float* __restrict__ lp1b,
    const float* __restrict__ lp2w, const float* __restrict__ lp2b,
    const float* __restrict__ ttab, const int* __restrict__ tix,
    const float* __restrict__ tw, const float* __restrict__ tb,
    const float* __restrict__ sh1w, const float* __restrict__ sh1b,
    const float* __restrict__ sh2w, const float* __restrict__ sh2b,
    float* __restrict__ lat, float* __restrict__ te, float* __restrict__ sizeo)
{
    const int b = blockIdx.x, c = threadIdx.x;
    __shared__ float S1[256], S2[256];
    if (c < 128) S1[c] = z[b * 128 + c];
    __syncthreads();
    // a1 = relu(z @ lp1 + b)
    float a1 = lp1b[c];
    #pragma unroll 4
    for (int k = 0; k < 128; ++k) a1 += S1[k] * lp1w[k * 256 + c];
    a1 = fmaxf(a1, 0.0f);
    __syncthreads();
    S2[c] = a1;
    __syncthreads();
    // lat = a1 @ lp2 + b
    float lv = lp2b[c];
    #pragma unroll 4
    for (int k = 0; k < 256; ++k) lv += S2[k] * lp2w[k * 256 + c];
    lat[b * 256 + c] = lv;
    S1[c] = lv;                 // S1 reads finished two barriers ago
    __syncthreads();
    // time_e = gelu(time_tab[t] @ tw + tb)
    S2[c] = ttab[tix[b] * 256 + c];
    __syncthreads();
    float tev = tb[c];
    #pragma unroll 4
    for (int k = 0; k < 256; ++k) tev += S2[k] * tw[k * 256 + c];
    te[b * 256 + c] = gelu_f(tev);
    // hid = relu(lat @ sh1 + b)   (128 wide)
    float hid = 0.0f;
    if (c < 128) {
        hid = sh1b[c];
        #pragma unroll 4
        for (int k = 0; k < 256; ++k) hid += S1[k] * sh1w[k * 128 + c];
        hid = fmaxf(hid, 0.0f);
    }
    __syncthreads();            // S2 reads (tev loop) done
    if (c < 128) S2[c] = hid;
    __syncthreads();
    float so = sh2b[c];
    #pragma unroll 4
    for (int k = 0; k < 128; ++k) so += S2[k] * sh2w[k * 256 + c];
    sizeo[b * 256 + c] = so;
}

// ---------------- embedding gather ----------------
__global__ __launch_bounds__(256) void k_embed(
    const int* __restrict__ tok, const float* __restrict__ tok_emb,
    const float* __restrict__ pos, const float* __restrict__ lat,
    const float* __restrict__ te, float* __restrict__ h)
{
    const int r = blockIdx.x;          // b*256+n
    const int c = threadIdx.x;
    const int b = r >> 8, n = r & 255;
    h[(size_t)r * 256 + c] = tok_emb[(size_t)tok[r] * 256 + c] + te[b * 256 + c]
                           + pos[n * 256 + c] + lat[b * 256 + c];
}

// ---------------- generic f32 GEMM: C = act(A @ W + bias) ----------------
// A: M x K (lda=K), W: K x N row-major, C: M x N with row stride ldc
#define TM 32
#define TN 64
#define TK 16
__global__ __launch_bounds__(256) void k_gemm(
    const float* __restrict__ A, const float* __restrict__ W, const float* __restrict__ bias,
    float* __restrict__ C, int M, int N, int K, int ldc, int act)
{
    __shared__ float As[TK][TM + 1];
    __shared__ float Ws[TK][TN];
    const int tid = threadIdx.x;
    const int m0 = blockIdx.y * TM, n0 = blockIdx.x * TN;
    const int tx = tid & 15, ty = tid >> 4;
    const int arow = tid >> 3, akk = (tid & 7) * 2;
    const int wkk = tid >> 4, wnn = (tid & 15) * 4;
    float acc[2][4] = {{0.f,0.f,0.f,0.f},{0.f,0.f,0.f,0.f}};
    for (int k0 = 0; k0 < K; k0 += TK) {
        float2 a2 = *(const float2*)(A + (size_t)(m0 + arow) * K + k0 + akk);
        As[akk][arow] = a2.x;
        As[akk + 1][arow] = a2.y;
        *(float4*)&Ws[wkk][wnn] = *(const float4*)(W + (size_t)(k0 + wkk) * N + n0 + wnn);
        __syncthreads();
        #pragma unroll
        for (int kk = 0; kk < TK; ++kk) {
            const float a0 = As[kk][ty * 2 + 0];
            const float a1 = As[kk][ty * 2 + 1];
            const float4 b4 = *(const float4*)&Ws[kk][tx * 4];
            acc[0][0] += a0 * b4.x; acc[0][1] += a0 * b4.y; acc[0][2] += a0 * b4.z; acc[0][3] += a0 * b4.w;
            acc[1][0] += a1 * b4.x; acc[1][1] += a1 * b4.y; acc[1][2] += a1 * b4.z; acc[1][3] += a1 * b4.w;
        }
        __syncthreads();
    }
    float4 bi = {0.f, 0.f, 0.f, 0.f};
    if (bias) bi = *(const float4*)(bias + n0 + tx * 4);
    #pragma unroll
    for (int i = 0; i < 2; ++i) {
        const int row = m0 + ty * 2 + i;
        float4 v;
        v.x = acc[i][0] + bi.x; v.y = acc[i][1] + bi.y;
        v.z = acc[i][2] + bi.z; v.w = acc[i][3] + bi.w;
        if (act == 1) {
            v.x = fmaxf(v.x, 0.f); v.y = fmaxf(v.y, 0.f);
            v.z = fmaxf(v.z, 0.f); v.w = fmaxf(v.w, 0.f);
        } else if (act == 2) {
            v.x = gelu_f(v.x); v.y = gelu_f(v.y); v.z = gelu_f(v.z); v.w = gelu_f(v.w);
        }
        *(float4*)(C + (size_t)row * ldc + n0 + tx * 4) = v;
    }
}

// ---------------- attention (optionally masked) ----------------
// qkv: (BN, ld) with q at col qo, k at ko, v at vo (each head hh uses cols +hh*64)
// out: (BN, 256) at col hh*64. mask: (B,N,N) uchar, mask[b,i,j]; null = dense.
__global__ __launch_bounds__(256) void k_attn(
    const float* __restrict__ qkv, int ld, int qo, int ko, int vo,
    const unsigned char* __restrict__ mask, float* __restrict__ out)
{
    const int blk = blockIdx.x;               // ((b*4+hh)*256 + i)
    const int i = blk & 255, hh = (blk >> 8) & 3, b = blk >> 10;
    const int tid = threadIdx.x;
    __shared__ float qs[64], aw[256], red[256], po[256];
    if (tid < 64) qs[tid] = qkv[(size_t)(b * 256 + i) * ld + qo + hh * 64 + tid];
    __syncthreads();
    const float* krow = qkv + (size_t)(b * 256 + tid) * ld + ko + hh * 64;
    float s = 0.f;
    #pragma unroll 8
    for (int d = 0; d < 64; ++d) s += qs[d] * krow[d];
    s *= 0.125f;
    bool ok = true;
    if (mask) { ok = mask[(size_t)(b * 256 + i) * 256 + tid] != 0; if (!ok) s = -1e30f; }
    red[tid] = s; __syncthreads();
    for (int off = 128; off > 0; off >>= 1) {
        if (tid < off) red[tid] = fmaxf(red[tid], red[tid + off]);
        __syncthreads();
    }
    const float mx = red[0];
    __syncthreads();
    const float e = (ok && mx > -1e29f) ? expf(s - mx) : 0.0f;
    red[tid] = e; __syncthreads();
    for (int off = 128; off > 0; off >>= 1) {
        if (tid < off) red[tid] += red[tid + off];
        __syncthreads();
    }
    const float sum = red[0];
    aw[tid] = (sum > 0.f) ? e / sum : 0.f;
    __syncthreads();
    const int part = tid >> 6, d = tid & 63;
    const float* vbase = qkv + (size_t)(b * 256) * ld + vo + hh * 64 + d;
    float acc = 0.f;
    #pragma unroll 4
    for (int jj = 0; jj < 64; ++jj) {
        const int j = part * 64 + jj;
        acc += aw[j] * vbase[(size_t)j * ld];
    }
    po[tid] = acc;
    __syncthreads();
    if (tid < 64) {
        const float o = po[tid] + po[64 + tid] + po[128 + tid] + po[192 + tid];
        out[(size_t)(b * 256 + i) * 256 + hh * 64 + tid] = o;
    }
}

// ---------------- fused residual LayerNorm: out = LN(a + b? + c?) * g + beta ----------------
__global__ __launch_bounds__(256) void k_ln(
    const float* __restrict__ a, const float* __restrict__ bb, int ldb,
    const float* __restrict__ cc, int ldc,
    const float* __restrict__ g, const float* __restrict__ beta, float* __restrict__ out)
{
    const int r = blockIdx.x, t = threadIdx.x;
    float v = a[(size_t)r * 256 + t];
    if (bb) v += bb[(size_t)r * ldb + t];
    if (cc) v += cc[(size_t)r * ldc + t];
    __shared__ float rs[256], rq[256];
    rs[t] = v; rq[t] = v * v;
    __syncthreads();
    for (int off = 128; off > 0; off >>= 1) {
        if (t < off) { rs[t] += rs[t + off]; rq[t] += rq[t + off]; }
        __syncthreads();
    }
    const float mean = rs[0] * (1.0f / 256.0f);
    const float var  = rq[0] * (1.0f / 256.0f) - mean * mean;
    out[(size_t)r * 256 + t] = (v - mean) * rsqrtf(var + 1e-5f) * g[t] + beta[t];
}

// ---------------- edge logits: val[b,i,j] = gelu(hi[b,i,:]+hj[b,j,:]) . w2 + b2 ----------------
// hi already contains +b1 (folded into its GEMM bias).
// mask_out (if set) gets the TRANSPOSED threshold: mask[b,j,i] = val > log(0.3/0.7)
__global__ __launch_bounds__(256) void k_edge(
    const float* __restrict__ hi, const float* __restrict__ hj,
    const float* __restrict__ w2, const float* __restrict__ b2,
    float* __restrict__ val_out, unsigned char* __restrict__ mask_out)
{
    const int blk = blockIdx.x;     // b*256 + i
    const int i = blk & 255, b = blk >> 8;
    const int j = threadIdx.x;
    __shared__ float his[256], w2s[256];
    his[j] = hi[(size_t)(b * 256 + i) * 256 + j];
    w2s[j] = w2[j];
    __syncthreads();
    const float* hjr = hj + (size_t)(b * 256 + j) * 256;
    float acc = 0.f;
    #pragma unroll 4
    for (int h = 0; h < 256; ++h) acc += gelu_f(his[h] + hjr[h]) * w2s[h];
    const float v = acc + b2[0];
    if (val_out)  val_out[(size_t)b * 65536 + i * 256 + j] = v;
    if (mask_out) mask_out[(size_t)b * 65536 + j * 256 + i] = (v > -0.84729786038720f) ? 1 : 0;
}

extern "C" void kernel_launch(void* const* d_in, const int* in_sizes, int n_in,
                              void* d_out, int out_size, void* d_ws, size_t ws_size,
                              hipStream_t stream) {
    const float* z     = (const float*)d_in[0];
    const int*   tok   = (const int*)d_in[1];
    const int*   tt    = (const int*)d_in[2];
    const float* lp1w  = (const float*)d_in[3];
    const float* lp1b  = (const float*)d_in[4];
    const float* lp2w  = (const float*)d_in[5];
    const float* lp2b  = (const float*)d_in[6];
    const float* temb  = (const float*)d_in[7];
    const float* ttab  = (const float*)d_in[8];
    const float* tw    = (const float*)d_in[9];
    const float* tb    = (const float*)d_in[10];
    const float* pos   = (const float*)d_in[11];
    const float* qkvw  = (const float*)d_in[12];
    const float* qkvb  = (const float*)d_in[13];
    const float* ow    = (const float*)d_in[14];
    const float* ob    = (const float*)d_in[15];
    const float* ln1g  = (const float*)d_in[16];
    const float* ln1b  = (const float*)d_in[17];
    const float* f1w   = (const float*)d_in[18];
    const float* f1b   = (const float*)d_in[19];
    const float* f2w   = (const float*)d_in[20];
    const float* f2b   = (const float*)d_in[21];
    const float* ln2g  = (const float*)d_in[22];
    const float* ln2b  = (const float*)d_in[23];
    const float* gqw   = (const float*)d_in[24];
    const float* gqb   = (const float*)d_in[25];
    const float* gkw   = (const float*)d_in[26];
    const float* gkb   = (const float*)d_in[27];
    const float* gvw   = (const float*)d_in[28];
    const float* gvb   = (const float*)d_in[29];
    const float* gsw   = (const float*)d_in[30];
    const float* gsb   = (const float*)d_in[31];
    const float* gl1g  = (const float*)d_in[32];
    const float* gl1b  = (const float*)d_in[33];
    const float* gf1w  = (const float*)d_in[34];
    const float* gf1b  = (const float*)d_in[35];
    const float* gf2w  = (const float*)d_in[36];
    const float* gf2b  = (const float*)d_in[37];
    const float* gl2g  = (const float*)d_in[38];
    const float* gl2b  = (const float*)d_in[39];
    const float* nh1w  = (const float*)d_in[40];
    const float* nh1b  = (const float*)d_in[41];
    const float* nh2w  = (const float*)d_in[42];
    const float* nh2b  = (const float*)d_in[43];
    const float* eh1w  = (const float*)d_in[44];
    const float* eh1b  = (const float*)d_in[45];
    const float* eh2w  = (const float*)d_in[46];
    const float* eh2b  = (const float*)d_in[47];
    const float* sh1w  = (const float*)d_in[48];
    const float* sh1b  = (const float*)d_in[49];
    const float* sh2w  = (const float*)d_in[50];
    const float* sh2b  = (const float*)d_in[51];

    float* W = (float*)d_ws;
    float* Hh  = W + 0;          // 262144  (B,N,H) activations, updated in place
    float* QK  = W + 262144;     // 1048576 qkv / qkvs / ffn hidden
    float* AO  = W + 1310720;    // 262144  attention out
    float* T1  = W + 1572864;    // 262144  proj out / ffn out / node hidden
    float* HI  = W + 1835008;    // 262144
    float* HJ  = W + 2097152;    // 262144
    float* LAT = W + 2359296;    // 1024
    float* TE  = W + 2360320;    // 1024
    unsigned char* MASK = (unsigned char*)(W + 2361344);   // 262144 bytes

    float* out      = (float*)d_out;
    float* out_node = out;
    float* out_edge = out + 262144;
    float* out_sz   = out + 524288;

    auto gemm = [&](const float* A, const float* Wt, const float* bias, float* C,
                    int M, int N, int K, int ldc, int act) {
        k_gemm<<<dim3(N / TN, M / TM), 256, 0, stream>>>(A, Wt, bias, C, M, N, K, ldc, act);
    };

    k_head0<<<4, 256, 0, stream>>>(z, lp1w, lp1b, lp2w, lp2b, ttab, tt, tw, tb,
                                   sh1w, sh1b, sh2w, sh2b, LAT, TE, out_sz);
    k_embed<<<1024, 256, 0, stream>>>(tok, temb, pos, LAT, TE, Hh);

    // ---- encoder x2 ----
    for (int l = 0; l < 2; ++l) {
        gemm(Hh, qkvw + (size_t)l * 196608, qkvb + l * 768, QK, 1024, 768, 256, 768, 0);
        k_attn<<<4096, 256, 0, stream>>>(QK, 768, 0, 256, 512, nullptr, AO);
        gemm(AO, ow + (size_t)l * 65536, ob + l * 256, T1, 1024, 256, 256, 256, 0);
        k_ln<<<1024, 256, 0, stream>>>(Hh, T1, 256, nullptr, 0, ln1g + l * 256, ln1b + l * 256, Hh);
        gemm(Hh, f1w + (size_t)l * 262144, f1b + l * 1024, QK, 1024, 1024, 256, 1024, 1);
        gemm(QK, f2w + (size_t)l * 262144, f2b + l * 256, T1, 1024, 256, 1024, 256, 0);
        k_ln<<<1024, 256, 0, stream>>>(Hh, T1, 256, nullptr, 0, ln2g + l * 256, ln2b + l * 256, Hh);
    }

    // ---- mask from el0(h) ----
    gemm(Hh, eh1w, eh1b, HI, 1024, 256, 256, 256, 0);            // +b1 folded
    gemm(Hh, eh1w + 65536, nullptr, HJ, 1024, 256, 256, 256, 0);
    k_edge<<<1024, 256, 0, stream>>>(HI, HJ, eh2w, eh2b, nullptr, MASK);

    // ---- GNN x4 ----
    for (int l = 0; l < 4; ++l) {
        gemm(Hh, gqw + (size_t)l * 65536, gqb + l * 256, QK + 0,   1024, 256, 256, 1024, 0);
        gemm(Hh, gkw + (size_t)l * 65536, gkb + l * 256, QK + 256, 1024, 256, 256, 1024, 0);
        gemm(Hh, gvw + (size_t)l * 65536, gvb + l * 256, QK + 512, 1024, 256, 256, 1024, 0);
        gemm(Hh, gsw + (size_t)l * 65536, gsb + l * 256, QK + 768, 1024, 256, 256, 1024, 0);
        k_attn<<<4096, 256, 0, stream>>>(QK, 1024, 0, 256, 512, MASK, AO);
        k_ln<<<1024, 256, 0, stream>>>(Hh, AO, 256, QK + 768, 1024, gl1g + l * 256, gl1b + l * 256, Hh);
        gemm(Hh, gf1w + (size_t)l * 262144, gf1b + l * 1024, QK, 1024, 1024, 256, 1024, 2);
        gemm(QK, gf2w + (size_t)l * 262144, gf2b + l * 256, T1, 1024, 256, 1024, 256, 0);
        k_ln<<<1024, 256, 0, stream>>>(Hh, T1, 256, nullptr, 0, gl2g + l * 256, gl2b + l * 256, Hh);
    }

    // ---- heads ----
    gemm(Hh, nh1w, nh1b, T1, 1024, 256, 256, 256, 2);
    gemm(T1, nh2w, nh2b, out_node, 1024, 256, 256, 256, 0);
    gemm(Hh, eh1w, eh1b, HI, 1024, 256, 256, 256, 0);
    gemm(Hh, eh1w + 65536, nullptr, HJ, 1024, 256, 256, 256, 0);
    k_edge<<<1024, 256, 0, stream>>>(HI, HJ, eh2w, eh2b, out_edge, nullptr);
}

// Round 4
// 1464.320 us; speedup vs baseline: 1.2923x; 1.2923x over previous
//
#include <hip/hip_runtime.h>
#include <math.h>

// B=4, N=256, H=256, HEADS=4, DH=64, FF=1024, V=256, L=128
// rows BN = 1024

// Branchless erf-based gelu (Abramowitz-Stegun 7.1.26, max abs err 1.5e-7).
// No branches -> no exec-mask divergence (libm erff has |x| regime branches).
__device__ __forceinline__ float gelu_f(float x) {
    const float y  = 0.70710678118654752f * x;     // erf argument
    const float ay = fabsf(y);
    const float t  = __builtin_amdgcn_rcpf(fmaf(0.3275911f, ay, 1.0f));
    float S = fmaf(t, 1.061405429f, -1.453152027f);
    S = fmaf(t, S, 1.421413741f);
    S = fmaf(t, S, -0.284496736f);
    S = fmaf(t, S, 0.254829592f);
    S = S * t;
    const float e = __expf(-ay * ay);
    const float E = fmaf(-S, e, 1.0f);             // 1 - S*exp(-ay^2), in [0,1]
    const float erfv = copysignf(E, y);
    return 0.5f * x * (1.0f + erfv);
}

// ---------------- stage 0: lat, time_e, size_logits ----------------
__global__ __launch_bounds__(256) void k_head0(
    const float* __restrict__ z, const float* __restrict__ lp1w, const float* __restrict__ lp1b,
    const float* __restrict__ lp2w, const float* __restrict__ lp2b,
    const float* __restrict__ ttab, const int* __restrict__ tix,
    const float* __restrict__ tw, const float* __restrict__ tb,
    const float* __restrict__ sh1w, const float* __restrict__ sh1b,
    const float* __restrict__ sh2w, const float* __restrict__ sh2b,
    float* __restrict__ lat, float* __restrict__ te, float* __restrict__ sizeo)
{
    const int b = blockIdx.x, c = threadIdx.x;
    __shared__ float S1[256], S2[256];
    if (c < 128) S1[c] = z[b * 128 + c];
    __syncthreads();
    // a1 = relu(z @ lp1 + b)
    float a1 = lp1b[c];
    #pragma unroll 4
    for (int k = 0; k < 128; ++k) a1 += S1[k] * lp1w[k * 256 + c];
    a1 = fmaxf(a1, 0.0f);
    __syncthreads();
    S2[c] = a1;
    __syncthreads();
    // lat = a1 @ lp2 + b
    float lv = lp2b[c];
    #pragma unroll 4
    for (int k = 0; k < 256; ++k) lv += S2[k] * lp2w[k * 256 + c];
    lat[b * 256 + c] = lv;
    S1[c] = lv;                 // S1 reads finished two barriers ago
    __syncthreads();
    // time_e = gelu(time_tab[t] @ tw + tb)
    S2[c] = ttab[tix[b] * 256 + c];
    __syncthreads();
    float tev = tb[c];
    #pragma unroll 4
    for (int k = 0; k < 256; ++k) tev += S2[k] * tw[k * 256 + c];
    te[b * 256 + c] = gelu_f(tev);
    // hid = relu(lat @ sh1 + b)   (128 wide)
    float hid = 0.0f;
    if (c < 128) {
        hid = sh1b[c];
        #pragma unroll 4
        for (int k = 0; k < 256; ++k) hid += S1[k] * sh1w[k * 128 + c];
        hid = fmaxf(hid, 0.0f);
    }
    __syncthreads();            // S2 reads (tev loop) done
    if (c < 128) S2[c] = hid;
    __syncthreads();
    float so = sh2b[c];
    #pragma unroll 4
    for (int k = 0; k < 128; ++k) so += S2[k] * sh2w[k * 256 + c];
    sizeo[b * 256 + c] = so;
}

// ---------------- embedding gather ----------------
__global__ __launch_bounds__(256) void k_embed(
    const int* __restrict__ tok, const float* __restrict__ tok_emb,
    const float* __restrict__ pos, const float* __restrict__ lat,
    const float* __restrict__ te, float* __restrict__ h)
{
    const int r = blockIdx.x;          // b*256+n
    const int c = threadIdx.x;
    const int b = r >> 8, n = r & 255;
    h[(size_t)r * 256 + c] = tok_emb[(size_t)tok[r] * 256 + c] + te[b * 256 + c]
                           + pos[n * 256 + c] + lat[b * 256 + c];
}

// ---------------- generic f32 GEMM: C = act(A @ W + bias) ----------------
// A: M x K (lda=K), W: K x N row-major, C: M x N with row stride ldc
#define TM 32
#define TN 64
#define TK 16
__global__ __launch_bounds__(256) void k_gemm(
    const float* __restrict__ A, const float* __restrict__ W, const float* __restrict__ bias,
    float* __restrict__ C, int M, int N, int K, int ldc, int act)
{
    __shared__ float As[TK][TM + 1];
    __shared__ float Ws[TK][TN];
    const int tid = threadIdx.x;
    const int m0 = blockIdx.y * TM, n0 = blockIdx.x * TN;
    const int tx = tid & 15, ty = tid >> 4;
    const int arow = tid >> 3, akk = (tid & 7) * 2;
    const int wkk = tid >> 4, wnn = (tid & 15) * 4;
    float acc[2][4] = {{0.f,0.f,0.f,0.f},{0.f,0.f,0.f,0.f}};
    for (int k0 = 0; k0 < K; k0 += TK) {
        float2 a2 = *(const float2*)(A + (size_t)(m0 + arow) * K + k0 + akk);
        As[akk][arow] = a2.x;
        As[akk + 1][arow] = a2.y;
        *(float4*)&Ws[wkk][wnn] = *(const float4*)(W + (size_t)(k0 + wkk) * N + n0 + wnn);
        __syncthreads();
        #pragma unroll
        for (int kk = 0; kk < TK; ++kk) {
            const float a0 = As[kk][ty * 2 + 0];
            const float a1 = As[kk][ty * 2 + 1];
            const float4 b4 = *(const float4*)&Ws[kk][tx * 4];
            acc[0][0] += a0 * b4.x; acc[0][1] += a0 * b4.y; acc[0][2] += a0 * b4.z; acc[0][3] += a0 * b4.w;
            acc[1][0] += a1 * b4.x; acc[1][1] += a1 * b4.y; acc[1][2] += a1 * b4.z; acc[1][3] += a1 * b4.w;
        }
        __syncthreads();
    }
    float4 bi = {0.f, 0.f, 0.f, 0.f};
    if (bias) bi = *(const float4*)(bias + n0 + tx * 4);
    #pragma unroll
    for (int i = 0; i < 2; ++i) {
        const int row = m0 + ty * 2 + i;
        float4 v;
        v.x = acc[i][0] + bi.x; v.y = acc[i][1] + bi.y;
        v.z = acc[i][2] + bi.z; v.w = acc[i][3] + bi.w;
        if (act == 1) {
            v.x = fmaxf(v.x, 0.f); v.y = fmaxf(v.y, 0.f);
            v.z = fmaxf(v.z, 0.f); v.w = fmaxf(v.w, 0.f);
        } else if (act == 2) {
            v.x = gelu_f(v.x); v.y = gelu_f(v.y); v.z = gelu_f(v.z); v.w = gelu_f(v.w);
        }
        *(float4*)(C + (size_t)row * ldc + n0 + tx * 4) = v;
    }
}

// ---------------- attention (optionally masked) ----------------
// qkv: (BN, ld) with q at col qo, k at ko, v at vo (each head hh uses cols +hh*64)
// out: (BN, 256) at col hh*64. mask: (B,N,N) uchar, mask[b,i,j]; null = dense.
__global__ __launch_bounds__(256) void k_attn(
    const float* __restrict__ qkv, int ld, int qo, int ko, int vo,
    const unsigned char* __restrict__ mask, float* __restrict__ out)
{
    const int blk = blockIdx.x;               // ((b*4+hh)*256 + i)
    const int i = blk & 255, hh = (blk >> 8) & 3, b = blk >> 10;
    const int tid = threadIdx.x;
    __shared__ float qs[64], aw[256], red[256], po[256];
    if (tid < 64) qs[tid] = qkv[(size_t)(b * 256 + i) * ld + qo + hh * 64 + tid];
    __syncthreads();
    const float* krow = qkv + (size_t)(b * 256 + tid) * ld + ko + hh * 64;
    float s = 0.f;
    #pragma unroll 8
    for (int d = 0; d < 64; ++d) s += qs[d] * krow[d];
    s *= 0.125f;
    bool ok = true;
    if (mask) { ok = mask[(size_t)(b * 256 + i) * 256 + tid] != 0; if (!ok) s = -1e30f; }
    red[tid] = s; __syncthreads();
    for (int off = 128; off > 0; off >>= 1) {
        if (tid < off) red[tid] = fmaxf(red[tid], red[tid + off]);
        __syncthreads();
    }
    const float mx = red[0];
    __syncthreads();
    const float e = (ok && mx > -1e29f) ? expf(s - mx) : 0.0f;
    red[tid] = e; __syncthreads();
    for (int off = 128; off > 0; off >>= 1) {
        if (tid < off) red[tid] += red[tid + off];
        __syncthreads();
    }
    const float sum = red[0];
    aw[tid] = (sum > 0.f) ? e / sum : 0.f;
    __syncthreads();
    const int part = tid >> 6, d = tid & 63;
    const float* vbase = qkv + (size_t)(b * 256) * ld + vo + hh * 64 + d;
    float acc = 0.f;
    #pragma unroll 4
    for (int jj = 0; jj < 64; ++jj) {
        const int j = part * 64 + jj;
        acc += aw[j] * vbase[(size_t)j * ld];
    }
    po[tid] = acc;
    __syncthreads();
    if (tid < 64) {
        const float o = po[tid] + po[64 + tid] + po[128 + tid] + po[192 + tid];
        out[(size_t)(b * 256 + i) * 256 + hh * 64 + tid] = o;
    }
}

// ---------------- fused residual LayerNorm: out = LN(a + b? + c?) * g + beta ----------------
__global__ __launch_bounds__(256) void k_ln(
    const float* __restrict__ a, const float* __restrict__ bb, int ldb,
    const float* __restrict__ cc, int ldc,
    const float* __restrict__ g, const float* __restrict__ beta, float* __restrict__ out)
{
    const int r = blockIdx.x, t = threadIdx.x;
    float v = a[(size_t)r * 256 + t];
    if (bb) v += bb[(size_t)r * ldb + t];
    if (cc) v += cc[(size_t)r * ldc + t];
    __shared__ float rs[256], rq[256];
    rs[t] = v; rq[t] = v * v;
    __syncthreads();
    for (int off = 128; off > 0; off >>= 1) {
        if (t < off) { rs[t] += rs[t + off]; rq[t] += rq[t + off]; }
        __syncthreads();
    }
    const float mean = rs[0] * (1.0f / 256.0f);
    const float var  = rq[0] * (1.0f / 256.0f) - mean * mean;
    out[(size_t)r * 256 + t] = (v - mean) * rsqrtf(var + 1e-5f) * g[t] + beta[t];
}

// ---------------- edge logits: val[b,i,j] = gelu(hi[b,i,:]+hj[b,j,:]) . w2 + b2 ----------------
// hi already contains +b1 (folded into its GEMM bias).
// mask_out (if set) gets the TRANSPOSED threshold: mask[b,j,i] = val > log(0.3/0.7)
__global__ __launch_bounds__(256) void k_edge(
    const float* __restrict__ hi, const float* __restrict__ hj,
    const float* __restrict__ w2, const float* __restrict__ b2,
    float* __restrict__ val_out, unsigned char* __restrict__ mask_out)
{
    const int blk = blockIdx.x;     // b*256 + i
    const int i = blk & 255, b = blk >> 8;
    const int j = threadIdx.x;
    __shared__ float his[256], w2s[256];
    his[j] = hi[(size_t)(b * 256 + i) * 256 + j];
    w2s[j] = w2[j];
    __syncthreads();
    const float4* hj4 = (const float4*)(hj + (size_t)(b * 256 + j) * 256);
    float acc = 0.f;
    #pragma unroll 4
    for (int h4 = 0; h4 < 64; ++h4) {
        const float4 hv = hj4[h4];
        const float4 hi4 = *(const float4*)&his[h4 * 4];
        const float4 w4  = *(const float4*)&w2s[h4 * 4];
        acc += gelu_f(hi4.x + hv.x) * w4.x;
        acc += gelu_f(hi4.y + hv.y) * w4.y;
        acc += gelu_f(hi4.z + hv.z) * w4.z;
        acc += gelu_f(hi4.w + hv.w) * w4.w;
    }
    const float v = acc + b2[0];
    if (val_out)  val_out[(size_t)b * 65536 + i * 256 + j] = v;
    if (mask_out) mask_out[(size_t)b * 65536 + j * 256 + i] = (v > -0.84729786038720f) ? 1 : 0;
}

extern "C" void kernel_launch(void* const* d_in, const int* in_sizes, int n_in,
                              void* d_out, int out_size, void* d_ws, size_t ws_size,
                              hipStream_t stream) {
    const float* z     = (const float*)d_in[0];
    const int*   tok   = (const int*)d_in[1];
    const int*   tt    = (const int*)d_in[2];
    const float* lp1w  = (const float*)d_in[3];
    const float* lp1b  = (const float*)d_in[4];
    const float* lp2w  = (const float*)d_in[5];
    const float* lp2b  = (const float*)d_in[6];
    const float* temb  = (const float*)d_in[7];
    const float* ttab  = (const float*)d_in[8];
    const float* tw    = (const float*)d_in[9];
    const float* tb    = (const float*)d_in[10];
    const float* pos   = (const float*)d_in[11];
    const float* qkvw  = (const float*)d_in[12];
    const float* qkvb  = (const float*)d_in[13];
    const float* ow    = (const float*)d_in[14];
    const float* ob    = (const float*)d_in[15];
    const float* ln1g  = (const float*)d_in[16];
    const float* ln1b  = (const float*)d_in[17];
    const float* f1w   = (const float*)d_in[18];
    const float* f1b   = (const float*)d_in[19];
    const float* f2w   = (const float*)d_in[20];
    const float* f2b   = (const float*)d_in[21];
    const float* ln2g  = (const float*)d_in[22];
    const float* ln2b  = (const float*)d_in[23];
    const float* gqw   = (const float*)d_in[24];
    const float* gqb   = (const float*)d_in[25];
    const float* gkw   = (const float*)d_in[26];
    const float* gkb   = (const float*)d_in[27];
    const float* gvw   = (const float*)d_in[28];
    const float* gvb   = (const float*)d_in[29];
    const float* gsw   = (const float*)d_in[30];
    const float* gsb   = (const float*)d_in[31];
    const float* gl1g  = (const float*)d_in[32];
    const float* gl1b  = (const float*)d_in[33];
    const float* gf1w  = (const float*)d_in[34];
    const float* gf1b  = (const float*)d_in[35];
    const float* gf2w  = (const float*)d_in[36];
    const float* gf2b  = (const float*)d_in[37];
    const float* gl2g  = (const float*)d_in[38];
    const float* gl2b  = (const float*)d_in[39];
    const float* nh1w  = (const float*)d_in[40];
    const float* nh1b  = (const float*)d_in[41];
    const float* nh2w  = (const float*)d_in[42];
    const float* nh2b  = (const float*)d_in[43];
    const float* eh1w  = (const float*)d_in[44];
    const float* eh1b  = (const float*)d_in[45];
    const float* eh2w  = (const float*)d_in[46];
    const float* eh2b  = (const float*)d_in[47];
    const float* sh1w  = (const float*)d_in[48];
    const float* sh1b  = (const float*)d_in[49];
    const float* sh2w  = (const float*)d_in[50];
    const float* sh2b  = (const float*)d_in[51];

    float* W = (float*)d_ws;
    float* Hh  = W + 0;          // 262144  (B,N,H) activations, updated in place
    float* QK  = W + 262144;     // 1048576 qkv / qkvs / ffn hidden
    float* AO  = W + 1310720;    // 262144  attention out
    float* T1  = W + 1572864;    // 262144  proj out / ffn out / node hidden
    float* HI  = W + 1835008;    // 262144
    float* HJ  = W + 2097152;    // 262144
    float* LAT = W + 2359296;    // 1024
    float* TE  = W + 2360320;    // 1024
    unsigned char* MASK = (unsigned char*)(W + 2361344);   // 262144 bytes

    float* out      = (float*)d_out;
    float* out_node = out;
    float* out_edge = out + 262144;
    float* out_sz   = out + 524288;

    auto gemm = [&](const float* A, const float* Wt, const float* bias, float* C,
                    int M, int N, int K, int ldc, int act) {
        k_gemm<<<dim3(N / TN, M / TM), 256, 0, stream>>>(A, Wt, bias, C, M, N, K, ldc, act);
    };

    k_head0<<<4, 256, 0, stream>>>(z, lp1w, lp1b, lp2w, lp2b, ttab, tt, tw, tb,
                                   sh1w, sh1b, sh2w, sh2b, LAT, TE, out_sz);
    k_embed<<<1024, 256, 0, stream>>>(tok, temb, pos, LAT, TE, Hh);

    // ---- encoder x2 ----
    for (int l = 0; l < 2; ++l) {
        gemm(Hh, qkvw + (size_t)l * 196608, qkvb + l * 768, QK, 1024, 768, 256, 768, 0);
        k_attn<<<4096, 256, 0, stream>>>(QK, 768, 0, 256, 512, nullptr, AO);
        gemm(AO, ow + (size_t)l * 65536, ob + l * 256, T1, 1024, 256, 256, 256, 0);
        k_ln<<<1024, 256, 0, stream>>>(Hh, T1, 256, nullptr, 0, ln1g + l * 256, ln1b + l * 256, Hh);
        gemm(Hh, f1w + (size_t)l * 262144, f1b + l * 1024, QK, 1024, 1024, 256, 1024, 1);
        gemm(QK, f2w + (size_t)l * 262144, f2b + l * 256, T1, 1024, 256, 1024, 256, 0);
        k_ln<<<1024, 256, 0, stream>>>(Hh, T1, 256, nullptr, 0, ln2g + l * 256, ln2b + l * 256, Hh);
    }

    // ---- mask from el0(h) ----
    gemm(Hh, eh1w, eh1b, HI, 1024, 256, 256, 256, 0);            // +b1 folded
    gemm(Hh, eh1w + 65536, nullptr, HJ, 1024, 256, 256, 256, 0);
    k_edge<<<1024, 256, 0, stream>>>(HI, HJ, eh2w, eh2b, nullptr, MASK);

    // ---- GNN x4 ----
    for (int l = 0; l < 4; ++l) {
        gemm(Hh, gqw + (size_t)l * 65536, gqb + l * 256, QK + 0,   1024, 256, 256, 1024, 0);
        gemm(Hh, gkw + (size_t)l * 65536, gkb + l * 256, QK + 256, 1024, 256, 256, 1024, 0);
        gemm(Hh, gvw + (size_t)l * 65536, gvb + l * 256, QK + 512, 1024, 256, 256, 1024, 0);
        gemm(Hh, gsw + (size_t)l * 65536, gsb + l * 256, QK + 768, 1024, 256, 256, 1024, 0);
        k_attn<<<4096, 256, 0, stream>>>(QK, 1024, 0, 256, 512, MASK, AO);
        k_ln<<<1024, 256, 0, stream>>>(Hh, AO, 256, QK + 768, 1024, gl1g + l * 256, gl1b + l * 256, Hh);
        gemm(Hh, gf1w + (size_t)l * 262144, gf1b + l * 1024, QK, 1024, 1024, 256, 1024, 2);
        gemm(QK, gf2w + (size_t)l * 262144, gf2b + l * 256, T1, 1024, 256, 1024, 256, 0);
        k_ln<<<1024, 256, 0, stream>>>(Hh, T1, 256, nullptr, 0, gl2g + l * 256, gl2b + l * 256, Hh);
    }

    // ---- heads ----
    gemm(Hh, nh1w, nh1b, T1, 1024, 256, 256, 256, 2);
    gemm(T1, nh2w, nh2b, out_node, 1024, 256, 256, 256, 0);
    gemm(Hh, eh1w, eh1b, HI, 1024, 256, 256, 256, 0);
    gemm(Hh, eh1w + 65536, nullptr, HJ, 1024, 256, 256, 256, 0);
    k_edge<<<1024, 256, 0, stream>>>(HI, HJ, eh2w, eh2b, out_edge, nullptr);
}

// Round 5
// 979.712 us; speedup vs baseline: 1.9316x; 1.4946x over previous
//
#include <hip/hip_runtime.h>
#include <math.h>

// B=4, N=256, H=256, HEADS=4, DH=64, FF=1024, V=256, L=128, rows BN=1024

// Branchless erf-based gelu (Abramowitz-Stegun 7.1.26, max abs err 1.5e-7).
__device__ __forceinline__ float gelu_f(float x) {
    const float y  = 0.70710678118654752f * x;
    const float ay = fabsf(y);
    const float t  = __builtin_amdgcn_rcpf(fmaf(0.3275911f, ay, 1.0f));
    float S = fmaf(t, 1.061405429f, -1.453152027f);
    S = fmaf(t, S, 1.421413741f);
    S = fmaf(t, S, -0.284496736f);
    S = fmaf(t, S, 0.254829592f);
    S = S * t;
    const float e = __expf(-ay * ay);
    const float E = fmaf(-S, e, 1.0f);
    return 0.5f * x * (1.0f + copysignf(E, y));
}

// ---------------- generic parallel matvec: out[r, c] = act(Arow . W[:,c] + bias) ----
// grid (R, N/64); 256 thr = 64 cols x 4 K-slices. A row optionally indexed (aidx).
__global__ __launch_bounds__(256) void k_mv(
    const float* __restrict__ A, const int* __restrict__ aidx, int K,
    const float* __restrict__ W, const float* __restrict__ bias,
    float* __restrict__ out, int N, int act)
{
    const int r = blockIdx.x, c0 = blockIdx.y * 64;
    const int c = threadIdx.x & 63, ks = threadIdx.x >> 6;
    const float* arow = A + (size_t)(aidx ? aidx[r] : r) * K;
    float s = 0.f;
    for (int k = ks; k < K; k += 4) s += arow[k] * W[(size_t)k * N + c0 + c];
    __shared__ float red[4][64];
    red[ks][c] = s;
    __syncthreads();
    if (ks == 0) {
        float v = red[0][c] + red[1][c] + red[2][c] + red[3][c] + (bias ? bias[c0 + c] : 0.f);
        if (act == 1) v = fmaxf(v, 0.f); else if (act == 2) v = gelu_f(v);
        out[(size_t)r * N + c0 + c] = v;
    }
}

// ---------------- embedding gather ----------------
__global__ __launch_bounds__(256) void k_embed(
    const int* __restrict__ tok, const float* __restrict__ tok_emb,
    const float* __restrict__ pos, const float* __restrict__ lat,
    const float* __restrict__ te, float* __restrict__ h)
{
    const int r = blockIdx.x, c = threadIdx.x;
    const int b = r >> 8, n = r & 255;
    h[(size_t)r * 256 + c] = tok_emb[(size_t)tok[r] * 256 + c] + te[b * 256 + c]
                           + pos[n * 256 + c] + lat[b * 256 + c];
}

// ---------------- f32 GEMM body (double-buffered reg prefetch) ----------------
#define TM 32
#define TN 64
#define TK 16
__device__ __forceinline__ void gemm_body(
    const float* __restrict__ A, const float* __restrict__ W, const float* __restrict__ bias,
    float* __restrict__ C, int N, int K, int ldc, int act, int m0, int n0)
{
    __shared__ float As[TK][TM + 1];
    __shared__ float Ws[TK][TN];
    const int tid = threadIdx.x;
    const int tx = tid & 15, ty = tid >> 4;
    const int arow = tid >> 3, akk = (tid & 7) * 2;
    const int wkk = tid >> 4, wnn = (tid & 15) * 4;
    const float* aptr = A + (size_t)(m0 + arow) * K + akk;
    const float* wptr = W + (size_t)wkk * N + n0 + wnn;
    float2 a2 = *(const float2*)aptr;
    float4 w4 = *(const float4*)wptr;
    float acc[2][4] = {{0.f,0.f,0.f,0.f},{0.f,0.f,0.f,0.f}};
    for (int k0 = 0; k0 < K; k0 += TK) {
        As[akk][arow] = a2.x;
        As[akk + 1][arow] = a2.y;
        *(float4*)&Ws[wkk][wnn] = w4;
        __syncthreads();
        if (k0 + TK < K) {                    // prefetch next tiles (hidden under FMAs)
            a2 = *(const float2*)(aptr + k0 + TK);
            w4 = *(const float4*)(wptr + (size_t)(k0 + TK) * N);
        }
        #pragma unroll
        for (int kk = 0; kk < TK; ++kk) {
            const float a0 = As[kk][ty * 2 + 0];
            const float a1 = As[kk][ty * 2 + 1];
            const float4 b4 = *(const float4*)&Ws[kk][tx * 4];
            acc[0][0] += a0 * b4.x; acc[0][1] += a0 * b4.y; acc[0][2] += a0 * b4.z; acc[0][3] += a0 * b4.w;
            acc[1][0] += a1 * b4.x; acc[1][1] += a1 * b4.y; acc[1][2] += a1 * b4.z; acc[1][3] += a1 * b4.w;
        }
        __syncthreads();
    }
    float4 bi = {0.f, 0.f, 0.f, 0.f};
    if (bias) bi = *(const float4*)(bias + n0 + tx * 4);
    #pragma unroll
    for (int i = 0; i < 2; ++i) {
        const int row = m0 + ty * 2 + i;
        float4 v;
        v.x = acc[i][0] + bi.x; v.y = acc[i][1] + bi.y;
        v.z = acc[i][2] + bi.z; v.w = acc[i][3] + bi.w;
        if (act == 1) {
            v.x = fmaxf(v.x, 0.f); v.y = fmaxf(v.y, 0.f);
            v.z = fmaxf(v.z, 0.f); v.w = fmaxf(v.w, 0.f);
        } else if (act == 2) {
            v.x = gelu_f(v.x); v.y = gelu_f(v.y); v.z = gelu_f(v.z); v.w = gelu_f(v.w);
        }
        *(float4*)(C + (size_t)row * ldc + n0 + tx * 4) = v;
    }
}

__global__ __launch_bounds__(256) void k_gemm(
    const float* __restrict__ A, const float* __restrict__ W, const float* __restrict__ bias,
    float* __restrict__ C, int N, int K, int ldc, int act)
{
    gemm_body(A, W, bias, C, N, K, ldc, act, blockIdx.y * TM, blockIdx.x * TN);
}

// 4 independent 256-col GEMMs sharing A (GNN q/k/v/s): blockIdx.z selects weights.
struct W4 { const float* w[4]; const float* b[4]; };
__global__ __launch_bounds__(256) void k_gemm4(
    const float* __restrict__ A, W4 p, float* __restrict__ C, int K, int act)
{
    const int z = blockIdx.z;
    gemm_body(A, p.w[z], p.b[z], C + z * 256, 256, K, 1024, act, blockIdx.y * TM, blockIdx.x * TN);
}

// ---------------- attention v2: block = (b, head, 16-row group) ----------------
// qkv: (BN, ld), q at qo, k at ko, v at vo (+hh*64 per head). out (BN,256) at hh*64.
// mask: (B,N,N) uchar or null.
__global__ __launch_bounds__(256) void k_attn2(
    const float* __restrict__ qkv, int ld, int qo, int ko, int vo,
    const unsigned char* __restrict__ mask, float* __restrict__ out)
{
    const int blk = blockIdx.x;              // b*64 + hh*16 + ig
    const int ig = blk & 15, hh = (blk >> 4) & 3, b = blk >> 6;
    const int i0 = ig * 16;
    const int t = threadIdx.x;
    __shared__ float Qs[16][68];             // padded: 4 distinct i per wave -> distinct banks
    __shared__ float Ts[64][68];             // K-tile then V-tile
    __shared__ float Ss[16][260];            // scores -> probabilities

    {   // load Q rows i0..i0+15
        const int r = t >> 4, c = (t & 15) * 4;
        *(float4*)&Qs[r][c] = *(const float4*)&qkv[(size_t)(b * 256 + i0 + r) * ld + qo + hh * 64 + c];
    }
    const int i = t >> 4, tx = t & 15;

    // ---- scores: S[i][j] = q_i . k_j ----
    for (int jt = 0; jt < 4; ++jt) {
        __syncthreads();                     // previous tile's compute done (also orders Qs)
        {   // stage K-tile [64][64]
            const int jr = t >> 2, cs = (t & 3) * 16;
            const float* src = &qkv[(size_t)(b * 256 + jt * 64 + jr) * ld + ko + hh * 64 + cs];
            *(float4*)&Ts[jr][cs + 0]  = *(const float4*)(src + 0);
            *(float4*)&Ts[jr][cs + 4]  = *(const float4*)(src + 4);
            *(float4*)&Ts[jr][cs + 8]  = *(const float4*)(src + 8);
            *(float4*)&Ts[jr][cs + 12] = *(const float4*)(src + 12);
        }
        __syncthreads();
        float s0 = 0.f, s1 = 0.f, s2 = 0.f, s3 = 0.f;
        #pragma unroll 8
        for (int d = 0; d < 64; ++d) {
            const float qd = Qs[i][d];
            s0 += qd * Ts[tx][d];
            s1 += qd * Ts[tx + 16][d];
            s2 += qd * Ts[tx + 32][d];
            s3 += qd * Ts[tx + 48][d];
        }
        Ss[i][jt * 64 + tx]      = s0;
        Ss[i][jt * 64 + tx + 16] = s1;
        Ss[i][jt * 64 + tx + 32] = s2;
        Ss[i][jt * 64 + tx + 48] = s3;
    }
    // Each thread's softmax slots (j % 16 == tx) are exactly the ones it wrote.

    // ---- masked softmax over j (row i), 16 lanes per row ----
    {
        const unsigned char* mrow = mask ? &mask[(size_t)(b * 256 + i0 + i) * 256] : nullptr;
        float sv[16]; bool okv[16];
        float m = -3.0e38f;
        #pragma unroll
        for (int k = 0; k < 16; ++k) {
            const int j = tx + 16 * k;
            const float s = Ss[i][j] * 0.125f;
            const bool ok = mrow ? (mrow[j] != 0) : true;
            sv[k] = s; okv[k] = ok;
            if (ok) m = fmaxf(m, s);
        }
        #pragma unroll
        for (int w = 1; w < 16; w <<= 1) m = fmaxf(m, __shfl_xor(m, w, 64));
        float ev[16]; float sum = 0.f;
        #pragma unroll
        for (int k = 0; k < 16; ++k) {
            ev[k] = okv[k] ? __expf(sv[k] - m) : 0.f;
            sum += ev[k];
        }
        #pragma unroll
        for (int w = 1; w < 16; w <<= 1) sum += __shfl_xor(sum, w, 64);
        const float inv = (sum > 0.f) ? 1.f / sum : 0.f;
        #pragma unroll
        for (int k = 0; k < 16; ++k) Ss[i][tx + 16 * k] = ev[k] * inv;
    }

    // ---- PV: out[i][d] = sum_j P[i][j] V[j][d] ----
    const int d4 = tx * 4;
    float4 o = {0.f, 0.f, 0.f, 0.f};
    for (int jt = 0; jt < 4; ++jt) {
        __syncthreads();                     // P final / previous V-tile reads done
        {   // stage V-tile
            const int jr = t >> 2, cs = (t & 3) * 16;
            const float* src = &qkv[(size_t)(b * 256 + jt * 64 + jr) * ld + vo + hh * 64 + cs];
            *(float4*)&Ts[jr][cs + 0]  = *(const float4*)(src + 0);
            *(float4*)&Ts[jr][cs + 4]  = *(const float4*)(src + 4);
            *(float4*)&Ts[jr][cs + 8]  = *(const float4*)(src + 8);
            *(float4*)&Ts[jr][cs + 12] = *(const float4*)(src + 12);
        }
        __syncthreads();
        #pragma unroll 8
        for (int j = 0; j < 64; ++j) {
            const float p = Ss[i][jt * 64 + j];
            const float4 v4 = *(const float4*)&Ts[j][d4];
            o.x += p * v4.x; o.y += p * v4.y; o.z += p * v4.z; o.w += p * v4.w;
        }
    }
    *(float4*)&out[(size_t)(b * 256 + i0 + i) * 256 + hh * 64 + d4] = o;
}

// ---------------- fused residual LayerNorm ----------------
__global__ __launch_bounds__(256) void k_ln(
    const float* __restrict__ a, const float* __restrict__ bb, int ldb,
    const float* __restrict__ cc, int ldc,
    const float* __restrict__ g, const float* __restrict__ beta, float* __restrict__ out)
{
    const int r = blockIdx.x, t = threadIdx.x;
    float v = a[(size_t)r * 256 + t];
    if (bb) v += bb[(size_t)r * ldb + t];
    if (cc) v += cc[(size_t)r * ldc + t];
    __shared__ float rs[256], rq[256];
    rs[t] = v; rq[t] = v * v;
    __syncthreads();
    for (int off = 128; off > 0; off >>= 1) {
        if (t < off) { rs[t] += rs[t + off]; rq[t] += rq[t + off]; }
        __syncthreads();
    }
    const float mean = rs[0] * (1.0f / 256.0f);
    const float var  = rq[0] * (1.0f / 256.0f) - mean * mean;
    out[(size_t)r * 256 + t] = (v - mean) * rsqrtf(var + 1e-5f) * g[t] + beta[t];
}

// ---------------- edge logits v2: 16x16 output tiles, LDS-staged ----------------
// val[b,i,j] = gelu(hi[b,i,:]+hj[b,j,:]) . w2 + b2;  mask_out[b,j,i] = val > thr
__global__ __launch_bounds__(256) void k_edge2(
    const float* __restrict__ hi, const float* __restrict__ hj,
    const float* __restrict__ w2, const float* __restrict__ b2,
    float* __restrict__ val_out, unsigned char* __restrict__ mask_out)
{
    const int jg = blockIdx.x, ig = blockIdx.y, b = blockIdx.z;
    const int t = threadIdx.x;
    __shared__ float his[16][260];
    __shared__ float hjs[16][260];
    __shared__ float w2s[256];
    {
        const int r = t >> 4, c = (t & 15) * 16;
        const float* s1 = &hi[(size_t)(b * 256 + ig * 16 + r) * 256 + c];
        const float* s2 = &hj[(size_t)(b * 256 + jg * 16 + r) * 256 + c];
        #pragma unroll
        for (int q = 0; q < 4; ++q) {
            *(float4*)&his[r][c + q * 4] = *(const float4*)(s1 + q * 4);
            *(float4*)&hjs[r][c + q * 4] = *(const float4*)(s2 + q * 4);
        }
        w2s[t] = w2[t];
    }
    __syncthreads();
    const int i = t >> 4, j = t & 15;
    float acc = 0.f;
    #pragma unroll 4
    for (int h = 0; h < 256; ++h) acc += gelu_f(his[i][h] + hjs[j][h]) * w2s[h];
    const float v = acc + b2[0];
    if (val_out)  val_out[(size_t)b * 65536 + (ig * 16 + i) * 256 + jg * 16 + j] = v;
    if (mask_out) mask_out[(size_t)b * 65536 + (jg * 16 + j) * 256 + ig * 16 + i] =
                      (v > -0.84729786038720f) ? 1 : 0;
}

extern "C" void kernel_launch(void* const* d_in, const int* in_sizes, int n_in,
                              void* d_out, int out_size, void* d_ws, size_t ws_size,
                              hipStream_t stream) {
    const float* z     = (const float*)d_in[0];
    const int*   tok   = (const int*)d_in[1];
    const int*   tt    = (const int*)d_in[2];
    const float* lp1w  = (const float*)d_in[3];
    const float* lp1b  = (const float*)d_in[4];
    const float* lp2w  = (const float*)d_in[5];
    const float* lp2b  = (const float*)d_in[6];
    const float* temb  = (const float*)d_in[7];
    const float* ttab  = (const float*)d_in[8];
    const float* tw    = (const float*)d_in[9];
    const float* tb    = (const float*)d_in[10];
    const float* pos   = (const float*)d_in[11];
    const float* qkvw  = (const float*)d_in[12];
    const float* qkvb  = (const float*)d_in[13];
    const float* ow    = (const float*)d_in[14];
    const float* ob    = (const float*)d_in[15];
    const float* ln1g  = (const float*)d_in[16];
    const float* ln1b  = (const float*)d_in[17];
    const float* f1w   = (const float*)d_in[18];
    const float* f1b   = (const float*)d_in[19];
    const float* f2w   = (const float*)d_in[20];
    const float* f2b   = (const float*)d_in[21];
    const float* ln2g  = (const float*)d_in[22];
    const float* ln2b  = (const float*)d_in[23];
    const float* gqw   = (const float*)d_in[24];
    const float* gqb   = (const float*)d_in[25];
    const float* gkw   = (const float*)d_in[26];
    const float* gkb   = (const float*)d_in[27];
    const float* gvw   = (const float*)d_in[28];
    const float* gvb   = (const float*)d_in[29];
    const float* gsw   = (const float*)d_in[30];
    const float* gsb   = (const float*)d_in[31];
    const float* gl1g  = (const float*)d_in[32];
    const float* gl1b  = (const float*)d_in[33];
    const float* gf1w  = (const float*)d_in[34];
    const float* gf1b  = (const float*)d_in[35];
    const float* gf2w  = (const float*)d_in[36];
    const float* gf2b  = (const float*)d_in[37];
    const float* gl2g  = (const float*)d_in[38];
    const float* gl2b  = (const float*)d_in[39];
    const float* nh1w  = (const float*)d_in[40];
    const float* nh1b  = (const float*)d_in[41];
    const float* nh2w  = (const float*)d_in[42];
    const float* nh2b  = (const float*)d_in[43];
    const float* eh1w  = (const float*)d_in[44];
    const float* eh1b  = (const float*)d_in[45];
    const float* eh2w  = (const float*)d_in[46];
    const float* eh2b  = (const float*)d_in[47];
    const float* sh1w  = (const float*)d_in[48];
    const float* sh1b  = (const float*)d_in[49];
    const float* sh2w  = (const float*)d_in[50];
    const float* sh2b  = (const float*)d_in[51];

    float* W = (float*)d_ws;
    float* Hh  = W + 0;          // 262144
    float* QK  = W + 262144;     // 1048576
    float* AO  = W + 1310720;    // 262144
    float* T1  = W + 1572864;    // 262144
    float* HI  = W + 1835008;    // 262144
    float* HJ  = W + 2097152;    // 262144
    float* LAT = W + 2359296;    // 1024
    float* TE  = W + 2360320;    // 1024
    float* A1  = W + 2361344;    // 1024
    float* SH  = W + 2362368;    // 512
    unsigned char* MASK = (unsigned char*)(W + 2362880);   // 262144 bytes

    float* out      = (float*)d_out;
    float* out_node = out;
    float* out_edge = out + 262144;
    float* out_sz   = out + 524288;

    auto gemm = [&](const float* A, const float* Wt, const float* bias, float* C,
                    int M, int N, int K, int ldc, int act) {
        k_gemm<<<dim3(N / TN, M / TM), 256, 0, stream>>>(A, Wt, bias, C, N, K, ldc, act);
    };

    // ---- stage 0: lat / time_e / size head (parallel matvecs) ----
    k_mv<<<dim3(4, 4), 256, 0, stream>>>(z,    nullptr, 128, lp1w, lp1b, A1,     256, 1);
    k_mv<<<dim3(4, 4), 256, 0, stream>>>(ttab, tt,      256, tw,   tb,   TE,     256, 2);
    k_mv<<<dim3(4, 4), 256, 0, stream>>>(A1,   nullptr, 256, lp2w, lp2b, LAT,    256, 0);
    k_mv<<<dim3(4, 2), 256, 0, stream>>>(LAT,  nullptr, 256, sh1w, sh1b, SH,     128, 1);
    k_mv<<<dim3(4, 4), 256, 0, stream>>>(SH,   nullptr, 128, sh2w, sh2b, out_sz, 256, 0);

    k_embed<<<1024, 256, 0, stream>>>(tok, temb, pos, LAT, TE, Hh);

    // ---- encoder x2 ----
    for (int l = 0; l < 2; ++l) {
        gemm(Hh, qkvw + (size_t)l * 196608, qkvb + l * 768, QK, 1024, 768, 256, 768, 0);
        k_attn2<<<256, 256, 0, stream>>>(QK, 768, 0, 256, 512, nullptr, AO);
        gemm(AO, ow + (size_t)l * 65536, ob + l * 256, T1, 1024, 256, 256, 256, 0);
        k_ln<<<1024, 256, 0, stream>>>(Hh, T1, 256, nullptr, 0, ln1g + l * 256, ln1b + l * 256, Hh);
        gemm(Hh, f1w + (size_t)l * 262144, f1b + l * 1024, QK, 1024, 1024, 256, 1024, 1);
        gemm(QK, f2w + (size_t)l * 262144, f2b + l * 256, T1, 1024, 256, 1024, 256, 0);
        k_ln<<<1024, 256, 0, stream>>>(Hh, T1, 256, nullptr, 0, ln2g + l * 256, ln2b + l * 256, Hh);
    }

    // ---- mask from el0(h) ----
    gemm(Hh, eh1w, eh1b, HI, 1024, 256, 256, 256, 0);            // +b1 folded
    gemm(Hh, eh1w + 65536, nullptr, HJ, 1024, 256, 256, 256, 0);
    k_edge2<<<dim3(16, 16, 4), 256, 0, stream>>>(HI, HJ, eh2w, eh2b, nullptr, MASK);

    // ---- GNN x4 ----
    for (int l = 0; l < 4; ++l) {
        W4 p;
        p.w[0] = gqw + (size_t)l * 65536; p.b[0] = gqb + l * 256;
        p.w[1] = gkw + (size_t)l * 65536; p.b[1] = gkb + l * 256;
        p.w[2] = gvw + (size_t)l * 65536; p.b[2] = gvb + l * 256;
        p.w[3] = gsw + (size_t)l * 65536; p.b[3] = gsb + l * 256;
        k_gemm4<<<dim3(4, 32, 4), 256, 0, stream>>>(Hh, p, QK, 256, 0);
        k_attn2<<<256, 256, 0, stream>>>(QK, 1024, 0, 256, 512, MASK, AO);
        k_ln<<<1024, 256, 0, stream>>>(Hh, AO, 256, QK + 768, 1024, gl1g + l * 256, gl1b + l * 256, Hh);
        gemm(Hh, gf1w + (size_t)l * 262144, gf1b + l * 1024, QK, 1024, 1024, 256, 1024, 2);
        gemm(QK, gf2w + (size_t)l * 262144, gf2b + l * 256, T1, 1024, 256, 1024, 256, 0);
        k_ln<<<1024, 256, 0, stream>>>(Hh, T1, 256, nullptr, 0, gl2g + l * 256, gl2b + l * 256, Hh);
    }

    // ---- heads ----
    gemm(Hh, nh1w, nh1b, T1, 1024, 256, 256, 256, 2);
    gemm(T1, nh2w, nh2b, out_node, 1024, 256, 256, 256, 0);
    gemm(Hh, eh1w, eh1b, HI, 1024, 256, 256, 256, 0);
    gemm(Hh, eh1w + 65536, nullptr, HJ, 1024, 256, 256, 256, 0);
    k_edge2<<<dim3(16, 16, 4), 256, 0, stream>>>(HI, HJ, eh2w, eh2b, out_edge, nullptr);
}

// Round 6
// 733.687 us; speedup vs baseline: 2.5793x; 1.3353x over previous
//
#include <hip/hip_runtime.h>
#include <math.h>

// B=4, N=256, H=256, HEADS=4, DH=64, FF=1024, V=256, L=128, rows BN=1024

typedef __attribute__((ext_vector_type(8))) short bf16x8;
typedef __attribute__((ext_vector_type(4))) float f32x4;

__device__ __forceinline__ unsigned short f2b(float f) {   // f32 -> bf16 RNE
    unsigned u = __float_as_uint(f);
    u += 0x7FFFu + ((u >> 16) & 1u);
    return (unsigned short)(u >> 16);
}
__device__ __forceinline__ unsigned pack2(float a, float b) {
    return (unsigned)f2b(a) | ((unsigned)f2b(b) << 16);
}
__device__ __forceinline__ bf16x8 as_frag(uint4 v) {
    union { uint4 u; bf16x8 f; } x; x.u = v; return x.f;
}

// Branchless erf-based gelu (A&S 7.1.26, max abs err 1.5e-7).
__device__ __forceinline__ float gelu_f(float x) {
    const float y  = 0.70710678118654752f * x;
    const float ay = fabsf(y);
    const float t  = __builtin_amdgcn_rcpf(fmaf(0.3275911f, ay, 1.0f));
    float S = fmaf(t, 1.061405429f, -1.453152027f);
    S = fmaf(t, S, 1.421413741f);
    S = fmaf(t, S, -0.284496736f);
    S = fmaf(t, S, 0.254829592f);
    S = S * t;
    const float e = __expf(-ay * ay);
    const float E = fmaf(-S, e, 1.0f);
    return 0.5f * x * (1.0f + copysignf(E, y));
}

// ---------------- weight prep: W (KxN f32) -> Wt (NxK bf16), all weights, one launch ----
struct PrepEnt { const float* src; unsigned dstOff; int K; int N; unsigned tstart; };
struct PrepTab { int n; PrepEnt e[36]; };

__global__ __launch_bounds__(256) void k_prep(PrepTab tab, unsigned short* __restrict__ wt)
{
    const int bx = blockIdx.x;
    int ei = 0;
    for (int i = 0; i < tab.n; ++i) if (tab.e[i].tstart <= (unsigned)bx) ei = i;
    const PrepEnt E = tab.e[ei];
    const int tIdx = bx - E.tstart;
    const int ntn = E.N >> 6;
    const int kt = tIdx / ntn, nt = tIdx % ntn;
    const int tid = threadIdx.x;
    __shared__ unsigned Tl[64][36];          // [k_local][n_local/2] bf16 pairs, row 144B
    {
        const int r = tid >> 2, c = (tid & 3) * 16;
        const float* s = E.src + (size_t)(kt * 64 + r) * E.N + nt * 64 + c;
        unsigned o[8];
        #pragma unroll
        for (int q = 0; q < 4; ++q) {
            const float4 v = *(const float4*)(s + q * 4);
            o[q * 2 + 0] = pack2(v.x, v.y);
            o[q * 2 + 1] = pack2(v.z, v.w);
        }
        *(uint4*)&Tl[r][c / 2 + 0] = make_uint4(o[0], o[1], o[2], o[3]);
        *(uint4*)&Tl[r][c / 2 + 4] = make_uint4(o[4], o[5], o[6], o[7]);
    }
    __syncthreads();
    {
        const int rn = tid >> 2, ck = (tid & 3) * 16;   // rn = n_local, ck = k_local base
        const int sh = (rn & 1) * 16, hw = rn >> 1;
        unsigned o[8];
        #pragma unroll
        for (int s = 0; s < 8; ++s) {
            const unsigned lo = (Tl[ck + 2 * s][hw] >> sh) & 0xFFFFu;
            const unsigned hi = (Tl[ck + 2 * s + 1][hw] >> sh) & 0xFFFFu;
            o[s] = lo | (hi << 16);
        }
        unsigned short* d = wt + E.dstOff + (size_t)(nt * 64 + rn) * E.K + kt * 64 + ck;
        *(uint4*)(d + 0) = make_uint4(o[0], o[1], o[2], o[3]);
        *(uint4*)(d + 8) = make_uint4(o[4], o[5], o[6], o[7]);
    }
}

// ---------------- MFMA GEMM body: C = act(A(f32,MxK) @ Wt(bf16,NxK)^T + bias) ----------
// 64x64 tile, 4 waves 2x2, each wave 32x32 via 4x mfma_f32_16x16x32_bf16. TK=32.
__device__ __forceinline__ void gemm_mfma_body(
    const float* __restrict__ A, const unsigned short* __restrict__ Wt,
    const float* __restrict__ bias, float* __restrict__ C,
    int K, int ldc, int act, int m0, int n0)
{
    __shared__ unsigned As_u[64][20];     // 64 rows x 32 bf16 (16 u32) + pad4, row 80B
    __shared__ unsigned Bs_u[64][20];
    const int tid = threadIdx.x;
    const int arow = tid >> 2, ac = tid & 3;               // ac*8 = k offset
    const float* ap = A + (size_t)(m0 + arow) * K + ac * 8;
    const unsigned short* bp = Wt + (size_t)(n0 + arow) * K + ac * 8;
    float4 av0 = *(const float4*)ap;
    float4 av1 = *(const float4*)(ap + 4);
    uint4  bv  = *(const uint4*)bp;
    f32x4 acc00 = {0.f,0.f,0.f,0.f}, acc01 = acc00, acc10 = acc00, acc11 = acc00;
    const int l = tid & 63, wid = tid >> 6;
    const int wm = wid & 1, wn = wid >> 1, lr = l & 15, lg = l >> 4;
    for (int k0 = 0; k0 < K; k0 += 32) {
        *(uint4*)&As_u[arow][ac * 4] = make_uint4(pack2(av0.x, av0.y), pack2(av0.z, av0.w),
                                                  pack2(av1.x, av1.y), pack2(av1.z, av1.w));
        *(uint4*)&Bs_u[arow][ac * 4] = bv;
        __syncthreads();
        if (k0 + 32 < K) {
            av0 = *(const float4*)(ap + k0 + 32);
            av1 = *(const float4*)(ap + k0 + 36);
            bv  = *(const uint4*)(bp + k0 + 32);
        }
        const bf16x8 fa0 = as_frag(*(const uint4*)&As_u[wm * 32 + lr][lg * 4]);
        const bf16x8 fa1 = as_frag(*(const uint4*)&As_u[wm * 32 + 16 + lr][lg * 4]);
        const bf16x8 fb0 = as_frag(*(const uint4*)&Bs_u[wn * 32 + lr][lg * 4]);
        const bf16x8 fb1 = as_frag(*(const uint4*)&Bs_u[wn * 32 + 16 + lr][lg * 4]);
        acc00 = __builtin_amdgcn_mfma_f32_16x16x32_bf16(fa0, fb0, acc00, 0, 0, 0);
        acc01 = __builtin_amdgcn_mfma_f32_16x16x32_bf16(fa0, fb1, acc01, 0, 0, 0);
        acc10 = __builtin_amdgcn_mfma_f32_16x16x32_bf16(fa1, fb0, acc10, 0, 0, 0);
        acc11 = __builtin_amdgcn_mfma_f32_16x16x32_bf16(fa1, fb1, acc11, 0, 0, 0);
        __syncthreads();
    }
    // epilogue: C[row][col], row=(lg*4+r) within 16-tile, col=lr
    const int cb0 = n0 + wn * 32 + lr, cb1 = cb0 + 16;
    const float b0 = bias ? bias[cb0] : 0.f;
    const float b1 = bias ? bias[cb1] : 0.f;
    #pragma unroll
    for (int r = 0; r < 4; ++r) {
        const int row0 = m0 + wm * 32 + lg * 4 + r;
        const int row1 = row0 + 16;
        float v00 = acc00[r] + b0, v01 = acc01[r] + b1;
        float v10 = acc10[r] + b0, v11 = acc11[r] + b1;
        if (act == 1) {
            v00 = fmaxf(v00, 0.f); v01 = fmaxf(v01, 0.f);
            v10 = fmaxf(v10, 0.f); v11 = fmaxf(v11, 0.f);
        } else if (act == 2) {
            v00 = gelu_f(v00); v01 = gelu_f(v01);
            v10 = gelu_f(v10); v11 = gelu_f(v11);
        }
        C[(size_t)row0 * ldc + cb0] = v00;
        C[(size_t)row0 * ldc + cb1] = v01;
        C[(size_t)row1 * ldc + cb0] = v10;
        C[(size_t)row1 * ldc + cb1] = v11;
    }
}

__global__ __launch_bounds__(256) void k_gemm_mfma(
    const float* __restrict__ A, const unsigned short* __restrict__ Wt,
    const float* __restrict__ bias, float* __restrict__ C, int K, int ldc, int act)
{
    gemm_mfma_body(A, Wt, bias, C, K, ldc, act, blockIdx.y * 64, blockIdx.x * 64);
}

// 4 independent N=256 GEMMs sharing A (GNN q/k/v/s): blockIdx.z selects weights.
struct MW4 { const unsigned short* wt[4]; const float* b[4]; };
__global__ __launch_bounds__(256) void k_gemm_mfma4(
    const float* __restrict__ A, MW4 p, float* __restrict__ C)
{
    const int z = blockIdx.z;
    gemm_mfma_body(A, p.wt[z], p.b[z], C + z * 256, 256, 1024, 0,
                   blockIdx.y * 64, blockIdx.x * 64);
}

// ---------------- generic parallel matvec (stage-0 heads) ----------------
__global__ __launch_bounds__(256) void k_mv(
    const float* __restrict__ A, const int* __restrict__ aidx, int K,
    const float* __restrict__ W, const float* __restrict__ bias,
    float* __restrict__ out, int N, int act)
{
    const int r = blockIdx.x, c0 = blockIdx.y * 64;
    const int c = threadIdx.x & 63, ks = threadIdx.x >> 6;
    const float* arow = A + (size_t)(aidx ? aidx[r] : r) * K;
    float s = 0.f;
    for (int k = ks; k < K; k += 4) s += arow[k] * W[(size_t)k * N + c0 + c];
    __shared__ float red[4][64];
    red[ks][c] = s;
    __syncthreads();
    if (ks == 0) {
        float v = red[0][c] + red[1][c] + red[2][c] + red[3][c] + (bias ? bias[c0 + c] : 0.f);
        if (act == 1) v = fmaxf(v, 0.f); else if (act == 2) v = gelu_f(v);
        out[(size_t)r * N + c0 + c] = v;
    }
}

// ---------------- embedding gather ----------------
__global__ __launch_bounds__(256) void k_embed(
    const int* __restrict__ tok, const float* __restrict__ tok_emb,
    const float* __restrict__ pos, const float* __restrict__ lat,
    const float* __restrict__ te, float* __restrict__ h)
{
    const int r = blockIdx.x, c = threadIdx.x;
    const int b = r >> 8, n = r & 255;
    h[(size_t)r * 256 + c] = tok_emb[(size_t)tok[r] * 256 + c] + te[b * 256 + c]
                           + pos[n * 256 + c] + lat[b * 256 + c];
}

// ---------------- attention: block = (b, head, 16-row group) ----------------
__global__ __launch_bounds__(256) void k_attn2(
    const float* __restrict__ qkv, int ld, int qo, int ko, int vo,
    const unsigned char* __restrict__ mask, float* __restrict__ out)
{
    const int blk = blockIdx.x;              // b*64 + hh*16 + ig
    const int ig = blk & 15, hh = (blk >> 4) & 3, b = blk >> 6;
    const int i0 = ig * 16;
    const int t = threadIdx.x;
    __shared__ float Qs[16][68];
    __shared__ float Ts[64][68];
    __shared__ float Ss[16][260];

    {
        const int r = t >> 4, c = (t & 15) * 4;
        *(float4*)&Qs[r][c] = *(const float4*)&qkv[(size_t)(b * 256 + i0 + r) * ld + qo + hh * 64 + c];
    }
    const int i = t >> 4, tx = t & 15;

    for (int jt = 0; jt < 4; ++jt) {
        __syncthreads();
        {
            const int jr = t >> 2, cs = (t & 3) * 16;
            const float* src = &qkv[(size_t)(b * 256 + jt * 64 + jr) * ld + ko + hh * 64 + cs];
            *(float4*)&Ts[jr][cs + 0]  = *(const float4*)(src + 0);
            *(float4*)&Ts[jr][cs + 4]  = *(const float4*)(src + 4);
            *(float4*)&Ts[jr][cs + 8]  = *(const float4*)(src + 8);
            *(float4*)&Ts[jr][cs + 12] = *(const float4*)(src + 12);
        }
        __syncthreads();
        float s0 = 0.f, s1 = 0.f, s2 = 0.f, s3 = 0.f;
        #pragma unroll 8
        for (int d = 0; d < 64; ++d) {
            const float qd = Qs[i][d];
            s0 += qd * Ts[tx][d];
            s1 += qd * Ts[tx + 16][d];
            s2 += qd * Ts[tx + 32][d];
            s3 += qd * Ts[tx + 48][d];
        }
        Ss[i][jt * 64 + tx]      = s0;
        Ss[i][jt * 64 + tx + 16] = s1;
        Ss[i][jt * 64 + tx + 32] = s2;
        Ss[i][jt * 64 + tx + 48] = s3;
    }

    {
        const unsigned char* mrow = mask ? &mask[(size_t)(b * 256 + i0 + i) * 256] : nullptr;
        float sv[16]; bool okv[16];
        float m = -3.0e38f;
        #pragma unroll
        for (int k = 0; k < 16; ++k) {
            const int j = tx + 16 * k;
            const float s = Ss[i][j] * 0.125f;
            const bool ok = mrow ? (mrow[j] != 0) : true;
            sv[k] = s; okv[k] = ok;
            if (ok) m = fmaxf(m, s);
        }
        #pragma unroll
        for (int w = 1; w < 16; w <<= 1) m = fmaxf(m, __shfl_xor(m, w, 64));
        float ev[16]; float sum = 0.f;
        #pragma unroll
        for (int k = 0; k < 16; ++k) {
            ev[k] = okv[k] ? __expf(sv[k] - m) : 0.f;
            sum += ev[k];
        }
        #pragma unroll
        for (int w = 1; w < 16; w <<= 1) sum += __shfl_xor(sum, w, 64);
        const float inv = (sum > 0.f) ? 1.f / sum : 0.f;
        #pragma unroll
        for (int k = 0; k < 16; ++k) Ss[i][tx + 16 * k] = ev[k] * inv;
    }

    const int d4 = tx * 4;
    float4 o = {0.f, 0.f, 0.f, 0.f};
    for (int jt = 0; jt < 4; ++jt) {
        __syncthreads();
        {
            const int jr = t >> 2, cs = (t & 3) * 16;
            const float* src = &qkv[(size_t)(b * 256 + jt * 64 + jr) * ld + vo + hh * 64 + cs];
            *(float4*)&Ts[jr][cs + 0]  = *(const float4*)(src + 0);
            *(float4*)&Ts[jr][cs + 4]  = *(const float4*)(src + 4);
            *(float4*)&Ts[jr][cs + 8]  = *(const float4*)(src + 8);
            *(float4*)&Ts[jr][cs + 12] = *(const float4*)(src + 12);
        }
        __syncthreads();
        #pragma unroll 8
        for (int j = 0; j < 64; ++j) {
            const float p = Ss[i][jt * 64 + j];
            const float4 v4 = *(const float4*)&Ts[j][d4];
            o.x += p * v4.x; o.y += p * v4.y; o.z += p * v4.z; o.w += p * v4.w;
        }
    }
    *(float4*)&out[(size_t)(b * 256 + i0 + i) * 256 + hh * 64 + d4] = o;
}

// ---------------- fused residual LayerNorm ----------------
__global__ __launch_bounds__(256) void k_ln(
    const float* __restrict__ a, const float* __restrict__ bb, int ldb,
    const float* __restrict__ cc, int ldc,
    const float* __restrict__ g, const float* __restrict__ beta, float* __restrict__ out)
{
    const int r = blockIdx.x, t = threadIdx.x;
    float v = a[(size_t)r * 256 + t];
    if (bb) v += bb[(size_t)r * ldb + t];
    if (cc) v += cc[(size_t)r * ldc + t];
    __shared__ float rs[256], rq[256];
    rs[t] = v; rq[t] = v * v;
    __syncthreads();
    for (int off = 128; off > 0; off >>= 1) {
        if (t < off) { rs[t] += rs[t + off]; rq[t] += rq[t + off]; }
        __syncthreads();
    }
    const float mean = rs[0] * (1.0f / 256.0f);
    const float var  = rq[0] * (1.0f / 256.0f) - mean * mean;
    out[(size_t)r * 256 + t] = (v - mean) * rsqrtf(var + 1e-5f) * g[t] + beta[t];
}

// ---------------- edge logits: 16x16 output tiles, LDS-staged ----------------
__global__ __launch_bounds__(256) void k_edge2(
    const float* __restrict__ hi, const float* __restrict__ hj,
    const float* __restrict__ w2, const float* __restrict__ b2,
    float* __restrict__ val_out, unsigned char* __restrict__ mask_out)
{
    const int jg = blockIdx.x, ig = blockIdx.y, b = blockIdx.z;
    const int t = threadIdx.x;
    __shared__ float his[16][260];
    __shared__ float hjs[16][260];
    __shared__ float w2s[256];
    {
        const int r = t >> 4, c = (t & 15) * 16;
        const float* s1 = &hi[(size_t)(b * 256 + ig * 16 + r) * 256 + c];
        const float* s2 = &hj[(size_t)(b * 256 + jg * 16 + r) * 256 + c];
        #pragma unroll
        for (int q = 0; q < 4; ++q) {
            *(float4*)&his[r][c + q * 4] = *(const float4*)(s1 + q * 4);
            *(float4*)&hjs[r][c + q * 4] = *(const float4*)(s2 + q * 4);
        }
        w2s[t] = w2[t];
    }
    __syncthreads();
    const int i = t >> 4, j = t & 15;
    float acc = 0.f;
    #pragma unroll 4
    for (int h = 0; h < 256; ++h) acc += gelu_f(his[i][h] + hjs[j][h]) * w2s[h];
    const float v = acc + b2[0];
    if (val_out)  val_out[(size_t)b * 65536 + (ig * 16 + i) * 256 + jg * 16 + j] = v;
    if (mask_out) mask_out[(size_t)b * 65536 + (jg * 16 + j) * 256 + ig * 16 + i] =
                      (v > -0.84729786038720f) ? 1 : 0;
}

extern "C" void kernel_launch(void* const* d_in, const int* in_sizes, int n_in,
                              void* d_out, int out_size, void* d_ws, size_t ws_size,
                              hipStream_t stream) {
    const float* z     = (const float*)d_in[0];
    const int*   tok   = (const int*)d_in[1];
    const int*   tt    = (const int*)d_in[2];
    const float* lp1w  = (const float*)d_in[3];
    const float* lp1b  = (const float*)d_in[4];
    const float* lp2w  = (const float*)d_in[5];
    const float* lp2b  = (const float*)d_in[6];
    const float* temb  = (const float*)d_in[7];
    const float* ttab  = (const float*)d_in[8];
    const float* tw    = (const float*)d_in[9];
    const float* tb    = (const float*)d_in[10];
    const float* pos   = (const float*)d_in[11];
    const float* qkvw  = (const float*)d_in[12];
    const float* qkvb  = (const float*)d_in[13];
    const float* ow    = (const float*)d_in[14];
    const float* ob    = (const float*)d_in[15];
    const float* ln1g  = (const float*)d_in[16];
    const float* ln1b  = (const float*)d_in[17];
    const float* f1w   = (const float*)d_in[18];
    const float* f1b   = (const float*)d_in[19];
    const float* f2w   = (const float*)d_in[20];
    const float* f2b   = (const float*)d_in[21];
    const float* ln2g  = (const float*)d_in[22];
    const float* ln2b  = (const float*)d_in[23];
    const float* gqw   = (const float*)d_in[24];
    const float* gqb   = (const float*)d_in[25];
    const float* gkw   = (const float*)d_in[26];
    const float* gkb   = (const float*)d_in[27];
    const float* gvw   = (const float*)d_in[28];
    const float* gvb   = (const float*)d_in[29];
    const float* gsw   = (const float*)d_in[30];
    const float* gsb   = (const float*)d_in[31];
    const float* gl1g  = (const float*)d_in[32];
    const float* gl1b  = (const float*)d_in[33];
    const float* gf1w  = (const float*)d_in[34];
    const float* gf1b  = (const float*)d_in[35];
    const float* gf2w  = (const float*)d_in[36];
    const float* gf2b  = (const float*)d_in[37];
    const float* gl2g  = (const float*)d_in[38];
    const float* gl2b  = (const float*)d_in[39];
    const float* nh1w  = (const float*)d_in[40];
    const float* nh1b  = (const float*)d_in[41];
    const float* nh2w  = (const float*)d_in[42];
    const float* nh2b  = (const float*)d_in[43];
    const float* eh1w  = (const float*)d_in[44];
    const float* eh1b  = (const float*)d_in[45];
    const float* eh2w  = (const float*)d_in[46];
    const float* eh2b  = (const float*)d_in[47];
    const float* sh1w  = (const float*)d_in[48];
    const float* sh1b  = (const float*)d_in[49];
    const float* sh2w  = (const float*)d_in[50];
    const float* sh2b  = (const float*)d_in[51];

    float* W = (float*)d_ws;
    float* Hh  = W + 0;          // 262144
    float* QK  = W + 262144;     // 1048576
    float* AO  = W + 1310720;    // 262144
    float* T1  = W + 1572864;    // 262144
    float* HI  = W + 1835008;    // 262144
    float* HJ  = W + 2097152;    // 262144
    float* LAT = W + 2359296;    // 1024
    float* TE  = W + 2360320;    // 1024
    float* A1  = W + 2361344;    // 1024
    float* SH  = W + 2362368;    // 512
    unsigned char* MASK = (unsigned char*)(W + 2362880);          // 262144 B
    unsigned short* wt  = (unsigned short*)(W + 2428416);         // bf16 Wt region, 9.96 MB

    float* out      = (float*)d_out;
    float* out_node = out;
    float* out_edge = out + 262144;
    float* out_sz   = out + 524288;

    // ---- build weight-transpose table (offsets in bf16 elems) ----
    PrepTab tab; int ne = 0; unsigned tiles = 0;
    auto add = [&](const float* src, int K, int N, unsigned off) {
        tab.e[ne].src = src; tab.e[ne].K = K; tab.e[ne].N = N;
        tab.e[ne].dstOff = off; tab.e[ne].tstart = tiles;
        tiles += (unsigned)((K >> 6) * (N >> 6)); ++ne;
    };
    for (int l = 0; l < 2; ++l) add(qkvw + (size_t)l * 196608, 256, 768,  0 + l * 196608);
    for (int l = 0; l < 2; ++l) add(ow   + (size_t)l * 65536,  256, 256,  393216 + l * 65536);
    for (int l = 0; l < 2; ++l) add(f1w  + (size_t)l * 262144, 256, 1024, 524288 + l * 262144);
    for (int l = 0; l < 2; ++l) add(f2w  + (size_t)l * 262144, 1024, 256, 1048576 + l * 262144);
    for (int l = 0; l < 4; ++l) add(gqw  + (size_t)l * 65536,  256, 256,  1572864 + l * 65536);
    for (int l = 0; l < 4; ++l) add(gkw  + (size_t)l * 65536,  256, 256,  1835008 + l * 65536);
    for (int l = 0; l < 4; ++l) add(gvw  + (size_t)l * 65536,  256, 256,  2097152 + l * 65536);
    for (int l = 0; l < 4; ++l) add(gsw  + (size_t)l * 65536,  256, 256,  2359296 + l * 65536);
    for (int l = 0; l < 4; ++l) add(gf1w + (size_t)l * 262144, 256, 1024, 2621440 + l * 262144);
    for (int l = 0; l < 4; ++l) add(gf2w + (size_t)l * 262144, 1024, 256, 3670016 + l * 262144);
    add(nh1w, 256, 256, 4718592);
    add(nh2w, 256, 256, 4784128);
    add(eh1w,         256, 256, 4849664);
    add(eh1w + 65536, 256, 256, 4915200);
    tab.n = ne;
    k_prep<<<tiles, 256, 0, stream>>>(tab, wt);

    auto gemmM = [&](const float* Aa, size_t wtoff, const float* bias, float* Cc,
                     int M, int N, int K, int ldc, int act) {
        k_gemm_mfma<<<dim3(N / 64, M / 64), 256, 0, stream>>>(Aa, wt + wtoff, bias, Cc, K, ldc, act);
    };

    // ---- stage 0 ----
    k_mv<<<dim3(4, 4), 256, 0, stream>>>(z,    nullptr, 128, lp1w, lp1b, A1,     256, 1);
    k_mv<<<dim3(4, 4), 256, 0, stream>>>(ttab, tt,      256, tw,   tb,   TE,     256, 2);
    k_mv<<<dim3(4, 4), 256, 0, stream>>>(A1,   nullptr, 256, lp2w, lp2b, LAT,    256, 0);
    k_mv<<<dim3(4, 2), 256, 0, stream>>>(LAT,  nullptr, 256, sh1w, sh1b, SH,     128, 1);
    k_mv<<<dim3(4, 4), 256, 0, stream>>>(SH,   nullptr, 128, sh2w, sh2b, out_sz, 256, 0);

    k_embed<<<1024, 256, 0, stream>>>(tok, temb, pos, LAT, TE, Hh);

    // ---- encoder x2 ----
    for (int l = 0; l < 2; ++l) {
        gemmM(Hh, (size_t)l * 196608, qkvb + l * 768, QK, 1024, 768, 256, 768, 0);
        k_attn2<<<256, 256, 0, stream>>>(QK, 768, 0, 256, 512, nullptr, AO);
        gemmM(AO, 393216 + (size_t)l * 65536, ob + l * 256, T1, 1024, 256, 256, 256, 0);
        k_ln<<<1024, 256, 0, stream>>>(Hh, T1, 256, nullptr, 0, ln1g + l * 256, ln1b + l * 256, Hh);
        gemmM(Hh, 524288 + (size_t)l * 262144, f1b + l * 1024, QK, 1024, 1024, 256, 1024, 1);
        gemmM(QK, 1048576 + (size_t)l * 262144, f2b + l * 256, T1, 1024, 256, 1024, 256, 0);
        k_ln<<<1024, 256, 0, stream>>>(Hh, T1, 256, nullptr, 0, ln2g + l * 256, ln2b + l * 256, Hh);
    }

    // ---- mask from el0(h) ----
    gemmM(Hh, 4849664, eh1b, HI, 1024, 256, 256, 256, 0);        // +b1 folded
    gemmM(Hh, 4915200, nullptr, HJ, 1024, 256, 256, 256, 0);
    k_edge2<<<dim3(16, 16, 4), 256, 0, stream>>>(HI, HJ, eh2w, eh2b, nullptr, MASK);

    // ---- GNN x4 ----
    for (int l = 0; l < 4; ++l) {
        MW4 p;
        p.wt[0] = wt + 1572864 + (size_t)l * 65536; p.b[0] = gqb + l * 256;
        p.wt[1] = wt + 1835008 + (size_t)l * 65536; p.b[1] = gkb + l * 256;
        p.wt[2] = wt + 2097152 + (size_t)l * 65536; p.b[2] = gvb + l * 256;
        p.wt[3] = wt + 2359296 + (size_t)l * 65536; p.b[3] = gsb + l * 256;
        k_gemm_mfma4<<<dim3(4, 16, 4), 256, 0, stream>>>(Hh, p, QK);
        k_attn2<<<256, 256, 0, stream>>>(QK, 1024, 0, 256, 512, MASK, AO);
        k_ln<<<1024, 256, 0, stream>>>(Hh, AO, 256, QK + 768, 1024, gl1g + l * 256, gl1b + l * 256, Hh);
        gemmM(Hh, 2621440 + (size_t)l * 262144, gf1b + l * 1024, QK, 1024, 1024, 256, 1024, 2);
        gemmM(QK, 3670016 + (size_t)l * 262144, gf2b + l * 256, T1, 1024, 256, 1024, 256, 0);
        k_ln<<<1024, 256, 0, stream>>>(Hh, T1, 256, nullptr, 0, gl2g + l * 256, gl2b + l * 256, Hh);
    }

    // ---- heads ----
    gemmM(Hh, 4718592, nh1b, T1, 1024, 256, 256, 256, 2);
    gemmM(T1, 4784128, nh2b, out_node, 1024, 256, 256, 256, 0);
    gemmM(Hh, 4849664, eh1b, HI, 1024, 256, 256, 256, 0);
    gemmM(Hh, 4915200, nullptr, HJ, 1024, 256, 256, 256, 0);
    k_edge2<<<dim3(16, 16, 4), 256, 0, stream>>>(HI, HJ, eh2w, eh2b, out_edge, nullptr);
}